// Round 2
// baseline (690.617 us; speedup 1.0000x reference)
//
#include <hip/hip_runtime.h>

#define NB 32
#define CC 64
#define HH 128
#define WW 128

typedef __attribute__((ext_vector_type(4))) float f32x4;
typedef __attribute__((ext_vector_type(8))) short s16x8;

__device__ __forceinline__ ushort f2bf(float f) {
    union { float f; unsigned u; } v; v.f = f;
    unsigned r = v.u + 0x7fffu + ((v.u >> 16) & 1u);   // RNE
    return (ushort)(r >> 16);
}

__global__ __launch_bounds__(512)
void col_attn_kernel(const float* __restrict__ x, const float* __restrict__ wq,
                     const float* __restrict__ wk, const float* __restrict__ wv,
                     const float* __restrict__ gama, float* __restrict__ out) {
    // LDS: 73728 + 10240 + 10240 + 17408 + 34816 = 146432 B (<160K)
    __shared__ ushort XT4[4][HH][72];   // x^T slab: [w][h][c], pad 72 (144B rows, 16B-aligned)
    __shared__ ushort QT[HH][40];       // Q^T: [h][q], pad 40 (80B rows)
    __shared__ ushort KT[HH][40];       // K^T: [h][q]
    __shared__ ushort VS[CC][136];      // V:   [c][h], pad 136 (272B rows)
    __shared__ ushort P [HH][136];      // softmax probs [i][j]

    const int tid  = threadIdx.x;
    const int lane = tid & 63;
    const int wid  = tid >> 6;      // wave 0..7
    const int g    = lane >> 4;     // 0..3
    const int fr   = lane & 15;     // 0..15

    const int bx = blockIdx.x;
    const int n  = bx >> 5;
    const int w0 = (bx & 31) * 4;

    const float gm = gama[0];
    const float* xn   = x   + (size_t)n * CC * HH * WW;
    float*       outn = out + (size_t)n * CC * HH * WW;

    // ---------------- phase 0: stage x slab (float4 over w) ----------------
    for (int idx = tid; idx < HH * CC; idx += 512) {
        int h = idx & (HH - 1);
        int c = idx >> 7;
        float4 v = *(const float4*)(xn + (c * HH + h) * WW + w0);
        XT4[0][h][c] = f2bf(v.x);
        XT4[1][h][c] = f2bf(v.y);
        XT4[2][h][c] = f2bf(v.z);
        XT4[3][h][c] = f2bf(v.w);
    }
    __syncthreads();

    f32x4 oacc[4][4];               // [wcol][c-tile] out^T fragments
    #pragma unroll
    for (int a = 0; a < 4; ++a)
        #pragma unroll
        for (int b = 0; b < 4; ++b) oacc[a][b] = (f32x4)0.0f;

    const int i0 = wid * 16;        // this wave's i-strip (and h-strip in ph1)

    #pragma unroll
    for (int wcol = 0; wcol < 4; ++wcol) {
        // ---------------- phase 1: QKV = X^T * W^T (K=64) ----------------
        s16x8 afrag0 = *(const s16x8*)&XT4[wcol][i0 + fr][ 0 + g * 8];
        s16x8 afrag1 = *(const s16x8*)&XT4[wcol][i0 + fr][32 + g * 8];
        #pragma unroll
        for (int ot = 0; ot < 8; ++ot) {
            int o = ot * 16 + fr;
            const float* wrow = (ot < 2) ? (wq + o * 64)
                              : (ot < 4) ? (wk + (o - 32) * 64)
                                         : (wv + (o - 64) * 64);
            f32x4 acc = (f32x4)0.0f;
            #pragma unroll
            for (int ks = 0; ks < 2; ++ks) {
                int c = ks * 32 + g * 8;
                float4 u0 = *(const float4*)(wrow + c);
                float4 u1 = *(const float4*)(wrow + c + 4);
                s16x8 bfrag;
                bfrag[0] = (short)f2bf(u0.x); bfrag[1] = (short)f2bf(u0.y);
                bfrag[2] = (short)f2bf(u0.z); bfrag[3] = (short)f2bf(u0.w);
                bfrag[4] = (short)f2bf(u1.x); bfrag[5] = (short)f2bf(u1.y);
                bfrag[6] = (short)f2bf(u1.z); bfrag[7] = (short)f2bf(u1.w);
                acc = __builtin_amdgcn_mfma_f32_16x16x32_bf16(
                          ks ? afrag1 : afrag0, bfrag, acc, 0, 0, 0);
            }
            #pragma unroll
            for (int r = 0; r < 4; ++r) {        // D: row=(g*4+r), col=fr  [verified C/D map]
                int h = i0 + g * 4 + r;
                ushort bv = f2bf(acc[r]);
                if (ot < 2)      QT[h][o] = bv;
                else if (ot < 4) KT[h][o - 32] = bv;
                else             VS[o - 64][h] = bv;
            }
        }
        __syncthreads();

        // ---------------- phase 2: S = Q^T K (K=32) ----------------
        s16x8 aQ = *(const s16x8*)&QT[i0 + fr][g * 8];
        f32x4 sf[8];
        #pragma unroll
        for (int jt = 0; jt < 8; ++jt) {
            s16x8 bK = *(const s16x8*)&KT[jt * 16 + fr][g * 8];
            sf[jt] = __builtin_amdgcn_mfma_f32_16x16x32_bf16(aQ, bK, (f32x4)0.0f, 0, 0, 0);
        }

        // ---------------- phase 3: softmax over j, P -> LDS ----------------
        #pragma unroll
        for (int r = 0; r < 4; ++r) {
            float m = sf[0][r];
            #pragma unroll
            for (int jt = 1; jt < 8; ++jt) m = fmaxf(m, sf[jt][r]);
            #pragma unroll
            for (int off = 1; off < 16; off <<= 1) m = fmaxf(m, __shfl_xor(m, off));
            float pv[8]; float sum = 0.0f;
            #pragma unroll
            for (int jt = 0; jt < 8; ++jt) { pv[jt] = __expf(sf[jt][r] - m); sum += pv[jt]; }
            #pragma unroll
            for (int off = 1; off < 16; off <<= 1) sum += __shfl_xor(sum, off);
            float inv = 1.0f / sum;
            int i = i0 + g * 4 + r;
            #pragma unroll
            for (int jt = 0; jt < 8; ++jt) P[i][jt * 16 + fr] = f2bf(pv[jt] * inv);
        }
        __syncthreads();

        // ---------------- phase 4: out^T = P * V^T (K=128) ----------------
        #pragma unroll
        for (int ks = 0; ks < 4; ++ks) {
            s16x8 aP = *(const s16x8*)&P[i0 + fr][ks * 32 + g * 8];
            #pragma unroll
            for (int ct = 0; ct < 4; ++ct) {
                s16x8 bV = *(const s16x8*)&VS[ct * 16 + fr][ks * 32 + g * 8];
                oacc[wcol][ct] = __builtin_amdgcn_mfma_f32_16x16x32_bf16(
                                     aP, bV, oacc[wcol][ct], 0, 0, 0);
            }
        }
        __syncthreads();   // QT/KT/VS/P reused next column
    }

    // ---------------- phase 5: out = gama*att + x (exact fp32), float4 ----------------
    #pragma unroll
    for (int ct = 0; ct < 4; ++ct) {
        #pragma unroll
        for (int r = 0; r < 4; ++r) {
            int c = ct * 16 + fr;
            int i = i0 + g * 4 + r;
            size_t off = (size_t)(c * HH + i) * WW + w0;
            float4 xv = *(const float4*)(xn + off);
            float4 ov;
            ov.x = gm * oacc[0][ct][r] + xv.x;
            ov.y = gm * oacc[1][ct][r] + xv.y;
            ov.z = gm * oacc[2][ct][r] + xv.z;
            ov.w = gm * oacc[3][ct][r] + xv.w;
            *(float4*)(outn + off) = ov;
        }
    }
}

extern "C" void kernel_launch(void* const* d_in, const int* in_sizes, int n_in,
                              void* d_out, int out_size, void* d_ws, size_t ws_size,
                              hipStream_t stream) {
    (void)in_sizes; (void)n_in; (void)out_size; (void)d_ws; (void)ws_size;
    const float* x    = (const float*)d_in[0];
    const float* wq   = (const float*)d_in[1];
    const float* wk   = (const float*)d_in[2];
    const float* wv   = (const float*)d_in[3];
    const float* gama = (const float*)d_in[4];
    float* out = (float*)d_out;
    hipLaunchKernelGGL(col_attn_kernel, dim3(NB * (WW / 4)), dim3(512), 0, stream,
                       x, wq, wk, wv, gama, out);
}

// Round 3
// 421.914 us; speedup vs baseline: 1.6369x; 1.6369x over previous
//
#include <hip/hip_runtime.h>

#define NN 32
#define CC 64
#define HH 128
#define WW 128
#define QK 32

typedef __attribute__((ext_vector_type(4))) float f32x4;
typedef __attribute__((ext_vector_type(8))) short s16x8;

__device__ __forceinline__ ushort f2bf(float f) {
    union { float f; unsigned u; } v; v.f = f;
    unsigned r = v.u + 0x7fffu + ((v.u >> 16) & 1u);   // RNE
    return (ushort)(r >> 16);
}
__device__ __forceinline__ float bf2f(ushort b) {
    union { unsigned u; float f; } v; v.u = ((unsigned)b) << 16; return v.f;
}

// ws element offsets (ushort units)
#define Q_OFF  0u
#define K_OFF  16777216u      // 32*128*128*32
#define V_OFF  33554432u
#define O_OFF  67108864u      // V is 32*128*128*64
#define WS_NEED_BYTES 201326592ull

// ============================ K1: QKV projection ============================
// block = (n, 16-w tile); loop 4 h-quarters. Full-line x reads; bf16 stores
// to [n][w][h][ch] layouts (ch contiguous -> 32B chunks, block-local lines).
__global__ __launch_bounds__(512)
void qkv_kernel(const float* __restrict__ x, const float* __restrict__ wq,
                const float* __restrict__ wk, const float* __restrict__ wv,
                ushort* __restrict__ ws) {
    __shared__ ushort XT[32][16][72];   // [hh][wl][c], pad 72 (144B rows, 16B-aligned)

    const int tid = threadIdx.x, lane = tid & 63, wid = tid >> 6;
    const int g = lane >> 4, fr = lane & 15;
    const int n = blockIdx.x >> 3, w0 = (blockIdx.x & 7) * 16;
    const float* xn = x + (size_t)n * CC * HH * WW;

    ushort* qws = ws + Q_OFF;
    ushort* kws = ws + K_OFF;
    ushort* vws = ws + V_OFF;

    // B fragments in regs: [ot][ks]; ot 0-1=Q, 2-3=K, 4-7=V; col o_local = fr
    s16x8 bfr[8][2];
    #pragma unroll
    for (int ot = 0; ot < 8; ++ot) {
        const float* wrow = (ot < 2) ? (wq + (ot * 16 + fr) * CC)
                          : (ot < 4) ? (wk + ((ot - 2) * 16 + fr) * CC)
                                     : (wv + ((ot - 4) * 16 + fr) * CC);
        #pragma unroll
        for (int ks = 0; ks < 2; ++ks) {
            float4 u0 = *(const float4*)(wrow + ks * 32 + g * 8);
            float4 u1 = *(const float4*)(wrow + ks * 32 + g * 8 + 4);
            s16x8 b;
            b[0] = (short)f2bf(u0.x); b[1] = (short)f2bf(u0.y);
            b[2] = (short)f2bf(u0.z); b[3] = (short)f2bf(u0.w);
            b[4] = (short)f2bf(u1.x); b[5] = (short)f2bf(u1.y);
            b[6] = (short)f2bf(u1.z); b[7] = (short)f2bf(u1.w);
            bfr[ot][ks] = b;
        }
    }

    for (int hq = 0; hq < 4; ++hq) {
        // stage x[c][hq*32+hh][w0..w0+15] -> XT[hh][wl][c]  (full 64B lines)
        #pragma unroll
        for (int i = 0; i < 16; ++i) {
            int flat = i * 512 + tid;          // 8192 = 64c * 32hh * 4q
            int q = flat & 3, row = flat >> 2;
            int hh = row & 31, c = row >> 5;
            float4 v = *(const float4*)(xn + ((c * HH + hq * 32 + hh) * WW + w0 + q * 4));
            XT[hh][q * 4 + 0][c] = f2bf(v.x);
            XT[hh][q * 4 + 1][c] = f2bf(v.y);
            XT[hh][q * 4 + 2][c] = f2bf(v.z);
            XT[hh][q * 4 + 3][c] = f2bf(v.w);
        }
        __syncthreads();

        #pragma unroll
        for (int t = 0; t < 4; ++t) {
            int hh = wid * 4 + t;
            int h  = hq * 32 + hh;
            s16x8 a0 = *(const s16x8*)&XT[hh][fr][g * 8];        // rows = wl
            s16x8 a1 = *(const s16x8*)&XT[hh][fr][32 + g * 8];
            #pragma unroll
            for (int ot = 0; ot < 8; ++ot) {
                f32x4 acc = (f32x4)0.0f;
                acc = __builtin_amdgcn_mfma_f32_16x16x32_bf16(a0, bfr[ot][0], acc, 0, 0, 0);
                acc = __builtin_amdgcn_mfma_f32_16x16x32_bf16(a1, bfr[ot][1], acc, 0, 0, 0);
                // D: row = wl = g*4+r, col = fr
                #pragma unroll
                for (int r = 0; r < 4; ++r) {
                    int w = w0 + g * 4 + r;
                    ushort bv = f2bf(acc[r]);
                    if (ot < 2)
                        qws[(((size_t)n * WW + w) * HH + h) * QK + ot * 16 + fr] = bv;
                    else if (ot < 4)
                        kws[(((size_t)n * WW + w) * HH + h) * QK + (ot - 2) * 16 + fr] = bv;
                    else
                        vws[(((size_t)n * WW + w) * HH + h) * CC + (ot - 4) * 16 + fr] = bv;
                }
            }
        }
        __syncthreads();
    }
}

// ============================ K2: column attention ============================
// block = one (n,w) column, 256 thr / 4 waves. Q,K frags direct from global;
// V transposed via LDS; P per-wave in LDS (no barrier needed for P).
__global__ __launch_bounds__(256)
void attn_kernel(const ushort* __restrict__ ws_in, ushort* __restrict__ ows) {
    __shared__ ushort P [HH][136];   // probs [i][j]        34816 B
    __shared__ ushort VS[CC][136];   // V^T   [c][j]        17408 B

    const int tid = threadIdx.x, lane = tid & 63, wid = tid >> 6;
    const int g = lane >> 4, fr = lane & 15;
    const int n = blockIdx.x >> 7, w = blockIdx.x & 127;

    const ushort* qcol = ws_in + Q_OFF + ((size_t)(n * WW + w)) * HH * QK;
    const ushort* kcol = ws_in + K_OFF + ((size_t)(n * WW + w)) * HH * QK;
    const ushort* vcol = ws_in + V_OFF + ((size_t)(n * WW + w)) * HH * CC;
    ushort*       ocol = ows          + ((size_t)(n * WW + w)) * HH * CC;

    // stage V: [h][c] global -> VS[c][h]
    #pragma unroll
    for (int i = 0; i < 4; ++i) {
        int flat = i * 256 + tid;          // 1024 = 128h * 8q
        int q = flat & 7, h = flat >> 3;
        s16x8 v8 = *(const s16x8*)(vcol + h * CC + q * 8);
        #pragma unroll
        for (int k = 0; k < 8; ++k) VS[q * 8 + k][h] = (ushort)v8[k];
    }

    const int i0 = wid * 32;

    // S + softmax per 16-row tile (sequential to cap VGPRs)
    #pragma unroll
    for (int tile = 0; tile < 2; ++tile) {
        int ib = i0 + tile * 16;
        s16x8 aQ = *(const s16x8*)(qcol + (ib + fr) * QK + g * 8);
        f32x4 sf[8];
        #pragma unroll
        for (int jt = 0; jt < 8; ++jt) {
            s16x8 bK = *(const s16x8*)(kcol + (jt * 16 + fr) * QK + g * 8);
            sf[jt] = __builtin_amdgcn_mfma_f32_16x16x32_bf16(aQ, bK, (f32x4)0.0f, 0, 0, 0);
        }
        #pragma unroll
        for (int r = 0; r < 4; ++r) {          // row i = ib + g*4 + r, col j = jt*16+fr
            float m = sf[0][r];
            #pragma unroll
            for (int jt = 1; jt < 8; ++jt) m = fmaxf(m, sf[jt][r]);
            #pragma unroll
            for (int off = 1; off < 16; off <<= 1) m = fmaxf(m, __shfl_xor(m, off));
            float pv[8]; float sum = 0.0f;
            #pragma unroll
            for (int jt = 0; jt < 8; ++jt) { pv[jt] = __expf(sf[jt][r] - m); sum += pv[jt]; }
            #pragma unroll
            for (int off = 1; off < 16; off <<= 1) sum += __shfl_xor(sum, off);
            float inv = 1.0f / sum;
            int i = ib + g * 4 + r;
            #pragma unroll
            for (int jt = 0; jt < 8; ++jt) P[i][jt * 16 + fr] = f2bf(pv[jt] * inv);
        }
    }
    __syncthreads();   // VS staged by all threads; (P rows are wave-local)

    // PV: out[i][c] = sum_j P[i][j] * V[c][j]
    #pragma unroll
    for (int tile = 0; tile < 2; ++tile) {
        int ib = i0 + tile * 16;
        #pragma unroll
        for (int ct = 0; ct < 4; ++ct) {
            f32x4 acc = (f32x4)0.0f;
            #pragma unroll
            for (int ks = 0; ks < 4; ++ks) {
                s16x8 aP = *(const s16x8*)&P[ib + fr][ks * 32 + g * 8];
                s16x8 bV = *(const s16x8*)&VS[ct * 16 + fr][ks * 32 + g * 8];
                acc = __builtin_amdgcn_mfma_f32_16x16x32_bf16(aP, bV, acc, 0, 0, 0);
            }
            // D: row = i-local = g*4+r, col = c = ct*16+fr ; Ows [h][c]
            #pragma unroll
            for (int r = 0; r < 4; ++r) {
                int i = ib + g * 4 + r;
                ocol[i * CC + ct * 16 + fr] = f2bf(acc[r]);
            }
        }
    }
}

// ============================ K3: epilogue transpose ============================
// out[n][c][h][w] = gama * Ows[n][w][h][c] + x[n][c][h][w]; full-line IO.
__global__ __launch_bounds__(256)
void epi_kernel(const ushort* __restrict__ ows, const float* __restrict__ x,
                const float* __restrict__ gama, float* __restrict__ out) {
    __shared__ ushort OT[CC][17][20];   // [c][hh][wl] pad: conflict-light, 8B-aligned reads

    const int tid = threadIdx.x;
    const int n  = blockIdx.x >> 6;
    const int h0 = ((blockIdx.x >> 3) & 7) * 16;
    const int w0 = (blockIdx.x & 7) * 16;
    const float gm = gama[0];
    const float* xn   = x   + (size_t)n * CC * HH * WW;
    float*       outn = out + (size_t)n * CC * HH * WW;

    // phase A: Ows tile -> OT (coalesced 16B reads, LDS scatter)
    #pragma unroll
    for (int i = 0; i < 8; ++i) {
        int flat = i * 256 + tid;          // 2048 = 16wl*16hh*8q
        int q = flat & 7, row = flat >> 3;
        int wl = row >> 4, hh = row & 15;
        s16x8 v8 = *(const s16x8*)(ows + ((size_t)(n * WW + w0 + wl) * HH + h0 + hh) * CC + q * 8);
        #pragma unroll
        for (int k = 0; k < 8; ++k) OT[q * 8 + k][hh][wl] = (ushort)v8[k];
    }
    __syncthreads();

    // phase B: per (c,hh) row: 16 w = full 64B line read x / write out
    #pragma unroll
    for (int i = 0; i < 16; ++i) {
        int flat = i * 256 + tid;          // 4096 = 64c*16hh*4q
        int q = flat & 3, row = flat >> 2;
        int c = row >> 4, hh = row & 15;
        size_t off = ((size_t)c * HH + h0 + hh) * WW + w0 + q * 4;
        float4 xv = *(const float4*)(xn + off);
        float4 ov;
        ov.x = gm * bf2f(OT[c][hh][q * 4 + 0]) + xv.x;
        ov.y = gm * bf2f(OT[c][hh][q * 4 + 1]) + xv.y;
        ov.z = gm * bf2f(OT[c][hh][q * 4 + 2]) + xv.z;
        ov.w = gm * bf2f(OT[c][hh][q * 4 + 3]) + xv.w;
        *(float4*)(outn + off) = ov;
    }
}

// ==================== fallback: round-0 fused kernel + XCD swizzle ====================
__global__ __launch_bounds__(512)
void col_attn_fused(const float* __restrict__ x, const float* __restrict__ wq,
                    const float* __restrict__ wk, const float* __restrict__ wv,
                    const float* __restrict__ gama, float* __restrict__ out) {
    __shared__ ushort XT4[4][HH][72];
    __shared__ ushort QT[HH][40];
    __shared__ ushort KT[HH][40];
    __shared__ ushort VS[CC][136];
    __shared__ ushort P [HH][136];

    const int tid = threadIdx.x, lane = tid & 63, wid = tid >> 6;
    const int g = lane >> 4, fr = lane & 15;
    const int bid = blockIdx.x;
    const int work = (bid & 7) * 128 + (bid >> 3);   // XCD-chunked, bijective (1024%8==0)
    const int n = work >> 5, w0 = (work & 31) * 4;

    const float gm = gama[0];
    const float* xn   = x   + (size_t)n * CC * HH * WW;
    float*       outn = out + (size_t)n * CC * HH * WW;

    for (int idx = tid; idx < HH * CC; idx += 512) {
        int h = idx & (HH - 1), c = idx >> 7;
        float4 v = *(const float4*)(xn + (c * HH + h) * WW + w0);
        XT4[0][h][c] = f2bf(v.x); XT4[1][h][c] = f2bf(v.y);
        XT4[2][h][c] = f2bf(v.z); XT4[3][h][c] = f2bf(v.w);
    }
    __syncthreads();

    f32x4 oacc[4][4];
    #pragma unroll
    for (int a = 0; a < 4; ++a)
        #pragma unroll
        for (int b = 0; b < 4; ++b) oacc[a][b] = (f32x4)0.0f;

    const int i0 = wid * 16;

    #pragma unroll
    for (int wcol = 0; wcol < 4; ++wcol) {
        s16x8 afrag0 = *(const s16x8*)&XT4[wcol][i0 + fr][ 0 + g * 8];
        s16x8 afrag1 = *(const s16x8*)&XT4[wcol][i0 + fr][32 + g * 8];
        #pragma unroll
        for (int ot = 0; ot < 8; ++ot) {
            int o = ot * 16 + fr;
            const float* wrow = (ot < 2) ? (wq + o * 64)
                              : (ot < 4) ? (wk + (o - 32) * 64)
                                         : (wv + (o - 64) * 64);
            f32x4 acc = (f32x4)0.0f;
            #pragma unroll
            for (int ks = 0; ks < 2; ++ks) {
                int c = ks * 32 + g * 8;
                float4 u0 = *(const float4*)(wrow + c);
                float4 u1 = *(const float4*)(wrow + c + 4);
                s16x8 bfrag;
                bfrag[0] = (short)f2bf(u0.x); bfrag[1] = (short)f2bf(u0.y);
                bfrag[2] = (short)f2bf(u0.z); bfrag[3] = (short)f2bf(u0.w);
                bfrag[4] = (short)f2bf(u1.x); bfrag[5] = (short)f2bf(u1.y);
                bfrag[6] = (short)f2bf(u1.z); bfrag[7] = (short)f2bf(u1.w);
                acc = __builtin_amdgcn_mfma_f32_16x16x32_bf16(
                          ks ? afrag1 : afrag0, bfrag, acc, 0, 0, 0);
            }
            #pragma unroll
            for (int r = 0; r < 4; ++r) {
                int h = i0 + g * 4 + r;
                ushort bv = f2bf(acc[r]);
                if (ot < 2)      QT[h][o] = bv;
                else if (ot < 4) KT[h][o - 32] = bv;
                else             VS[o - 64][h] = bv;
            }
        }
        __syncthreads();

        s16x8 aQ = *(const s16x8*)&QT[i0 + fr][g * 8];
        f32x4 sf[8];
        #pragma unroll
        for (int jt = 0; jt < 8; ++jt) {
            s16x8 bK = *(const s16x8*)&KT[jt * 16 + fr][g * 8];
            sf[jt] = __builtin_amdgcn_mfma_f32_16x16x32_bf16(aQ, bK, (f32x4)0.0f, 0, 0, 0);
        }
        #pragma unroll
        for (int r = 0; r < 4; ++r) {
            float m = sf[0][r];
            #pragma unroll
            for (int jt = 1; jt < 8; ++jt) m = fmaxf(m, sf[jt][r]);
            #pragma unroll
            for (int off = 1; off < 16; off <<= 1) m = fmaxf(m, __shfl_xor(m, off));
            float pv[8]; float sum = 0.0f;
            #pragma unroll
            for (int jt = 0; jt < 8; ++jt) { pv[jt] = __expf(sf[jt][r] - m); sum += pv[jt]; }
            #pragma unroll
            for (int off = 1; off < 16; off <<= 1) sum += __shfl_xor(sum, off);
            float inv = 1.0f / sum;
            int i = i0 + g * 4 + r;
            #pragma unroll
            for (int jt = 0; jt < 8; ++jt) P[i][jt * 16 + fr] = f2bf(pv[jt] * inv);
        }
        __syncthreads();

        #pragma unroll
        for (int ks = 0; ks < 4; ++ks) {
            s16x8 aP = *(const s16x8*)&P[i0 + fr][ks * 32 + g * 8];
            #pragma unroll
            for (int ct = 0; ct < 4; ++ct) {
                s16x8 bV = *(const s16x8*)&VS[ct * 16 + fr][ks * 32 + g * 8];
                oacc[wcol][ct] = __builtin_amdgcn_mfma_f32_16x16x32_bf16(
                                     aP, bV, oacc[wcol][ct], 0, 0, 0);
            }
        }
        __syncthreads();
    }

    #pragma unroll
    for (int ct = 0; ct < 4; ++ct) {
        #pragma unroll
        for (int r = 0; r < 4; ++r) {
            int c = ct * 16 + fr;
            int i = i0 + g * 4 + r;
            size_t off = (size_t)(c * HH + i) * WW + w0;
            float4 xv = *(const float4*)(xn + off);
            float4 ov;
            ov.x = gm * oacc[0][ct][r] + xv.x;
            ov.y = gm * oacc[1][ct][r] + xv.y;
            ov.z = gm * oacc[2][ct][r] + xv.z;
            ov.w = gm * oacc[3][ct][r] + xv.w;
            *(float4*)(outn + off) = ov;
        }
    }
}

extern "C" void kernel_launch(void* const* d_in, const int* in_sizes, int n_in,
                              void* d_out, int out_size, void* d_ws, size_t ws_size,
                              hipStream_t stream) {
    (void)in_sizes; (void)n_in; (void)out_size;
    const float* x    = (const float*)d_in[0];
    const float* wq   = (const float*)d_in[1];
    const float* wk   = (const float*)d_in[2];
    const float* wv   = (const float*)d_in[3];
    const float* gama = (const float*)d_in[4];
    float* out = (float*)d_out;

    if (ws_size >= WS_NEED_BYTES) {
        ushort* ws = (ushort*)d_ws;
        hipLaunchKernelGGL(qkv_kernel, dim3(NN * 8), dim3(512), 0, stream,
                           x, wq, wk, wv, ws);
        hipLaunchKernelGGL(attn_kernel, dim3(NN * WW), dim3(256), 0, stream,
                           ws, ws + O_OFF);
        hipLaunchKernelGGL(epi_kernel, dim3(NN * 8 * 8), dim3(256), 0, stream,
                           ws + O_OFF, x, gama, out);
    } else {
        hipLaunchKernelGGL(col_attn_fused, dim3(NN * (WW / 4)), dim3(512), 0, stream,
                           x, wq, wk, wv, gama, out);
    }
}